// Round 15
// baseline (167.102 us; speedup 1.0000x reference)
//
#include <hip/hip_runtime.h>
#include <hip/hip_bf16.h>
#include <cstddef>
#include <cstdint>

typedef __attribute__((ext_vector_type(8))) short short8;  // 8 bf16 in 4 VGPRs
typedef __attribute__((ext_vector_type(4))) float f32x4;

constexpr int Bsz = 2048, Tsz = 120, Ksz = 128;
constexpr float L2E = 1.44269504088896340736f;  // log2(e)
constexpr float LN2 = 0.69314718055994530942f;  // ln(2)

__device__ __forceinline__ int expbits(float x) {
  return (int)(__float_as_uint(x) >> 23) - 127;   // floor(log2 x), x > 0
}

// dst.lo = bf16(a), dst.hi = bf16(b)  (T12 recipe: no builtin on gfx950)
__device__ __forceinline__ uint32_t cvtpk_bf16(float a, float b) {
  uint32_t d;
  asm("v_cvt_pk_bf16_f32 %0, %1, %2" : "=v"(d) : "v"(a), "v"(b));
  return d;
}

// drain own LDS ops -> barrier; memory clobbers, no sched pin.
#define BAR() do {                                        \
    asm volatile("s_waitcnt lgkmcnt(0)" ::: "memory");    \
    __builtin_amdgcn_s_barrier();                         \
    asm volatile("" ::: "memory");                        \
  } while (0)

// TWO independent 16-batch chains (A,B) fused per block: 4 waves x 32 real
// batches, 64 blocks. One barrier per fused step serves both chains; each
// chain's LDS/MFMA latency hides under the other's issue (r12 showed the
// step window is mostly idle slack). Math per chain = r14 (green):
// linear-space recursion, P bf16 in LDS, stale gain-1/4 controller
// Df_{t+1} = 7 + (z_{t-1}>>2). Ef registers shared by both chains.
__global__ __launch_bounds__(256) void crf_fwd(
    const float* __restrict__ emis,   // [B,T,K]
    const int* __restrict__ tag,      // [B,T]
    const int* __restrict__ maskg,    // [B,T]
    const float* __restrict__ Tg,     // [K,K]
    float* __restrict__ nll)          // [B]
{
  __shared__ __align__(16) uint2 Pb[2][2][16 * 32];   // [chain][dbuf][col][st/4]
  __shared__ __align__(16) float lamp[2][2][16][20];  // [chain][dbuf] partials
  __shared__ int maskLds[Tsz * 32];                   // [t][col 0..31]

  const int tid = threadIdx.x;
  const int w = tid >> 6, lane = tid & 63;
  const int c = lane & 15, hi = lane >> 4;
  const int b0 = blockIdx.x * 32;
  const int sw2 = (c & 7) << 1;                       // XOR swizzle, uint2
  const int slot = 4 * w + hi;                        // 0..15

  const int soff = 32 * w + 4 * hi;
  const float* epA = emis + (size_t)(b0 + c) * Tsz * Ksz + soff;
  const float* epB = emis + (size_t)(b0 + 16 + c) * Tsz * Ksz + soff;

  // early emission loads: t=0 (alpha0), t=1 (c2 seed), t=2,3 (pipeline)
  f32x4 a0A[2], r1A[2], rPA[2], rQA[2];
  f32x4 a0B[2], r1B[2], rPB[2], rQB[2];
  a0A[0] = *(const f32x4*)(epA);           a0A[1] = *(const f32x4*)(epA + 16);
  a0B[0] = *(const f32x4*)(epB);           a0B[1] = *(const f32x4*)(epB + 16);
  r1A[0] = *(const f32x4*)(epA + Ksz);     r1A[1] = *(const f32x4*)(epA + Ksz + 16);
  r1B[0] = *(const f32x4*)(epB + Ksz);     r1B[1] = *(const f32x4*)(epB + Ksz + 16);
  rPA[0] = *(const f32x4*)(epA + 2 * Ksz); rPA[1] = *(const f32x4*)(epA + 2 * Ksz + 16);
  rPB[0] = *(const f32x4*)(epB + 2 * Ksz); rPB[1] = *(const f32x4*)(epB + 2 * Ksz + 16);
  rQA[0] = *(const f32x4*)(epA + 3 * Ksz); rQA[1] = *(const f32x4*)(epA + 3 * Ksz + 16);
  rQB[0] = *(const f32x4*)(epB + 3 * Ksz); rQB[1] = *(const f32x4*)(epB + 3 * Ksz + 16);

  // stage masks for 32 cols
  for (int i = tid; i < Tsz * 32; i += 256) {
    int col = i & 31, tt = i >> 5;
    maskLds[i] = maskg[(size_t)(b0 + col) * Tsz + tt];
  }

  // E^T A-fragments (shared by both chains):
  // Ef[rti][m][j] = bf16(exp(T[32m+8hi+j][32w+16rti+c]))
  short8 Ef[2][4];
  #pragma unroll
  for (int rti = 0; rti < 2; ++rti)
    #pragma unroll
    for (int m = 0; m < 4; ++m) {
      short8 v;
      #pragma unroll
      for (int j = 0; j < 8; ++j) {
        union { __hip_bfloat16 h; short s; } cv;
        cv.h = __float2bfloat16(
            __expf(Tg[(size_t)(32 * m + 8 * hi + j) * Ksz + 32 * w + 16 * rti + c]));
        v[j] = cv.s;
      }
      Ef[rti][m] = v;
    }

  // ---- prologue: per-col max of alpha0 for both chains
  {
    float pmA = fmaxf(fmaxf(fmaxf(a0A[0][0], a0A[0][1]), fmaxf(a0A[0][2], a0A[0][3])),
                      fmaxf(fmaxf(a0A[1][0], a0A[1][1]), fmaxf(a0A[1][2], a0A[1][3])));
    float pmB = fmaxf(fmaxf(fmaxf(a0B[0][0], a0B[0][1]), fmaxf(a0B[0][2], a0B[0][3])),
                      fmaxf(fmaxf(a0B[1][0], a0B[1][1]), fmaxf(a0B[1][2], a0B[1][3])));
    lamp[0][1][c][slot] = pmA;
    lamp[1][1][c][slot] = pmB;
  }
  BAR();
  float nRegA, nRegB;
  f32x4 PvA[2], PvB[2];
  {
    const float* lrA = &lamp[0][1][c][0];
    const float* lrB = &lamp[1][1][c][0];
    f32x4 mmA, mmB;
    #pragma unroll
    for (int r = 0; r < 4; ++r) {
      mmA[r] = fmaxf(fmaxf(lrA[r], lrA[r + 4]), fmaxf(lrA[r + 8], lrA[r + 12]));
      mmB[r] = fmaxf(fmaxf(lrB[r], lrB[r + 4]), fmaxf(lrB[r + 8], lrB[r + 12]));
    }
    float mxA = fmaxf(fmaxf(mmA[0], mmA[1]), fmaxf(mmA[2], mmA[3]));
    float mxB = fmaxf(fmaxf(mmB[0], mmB[1]), fmaxf(mmB[2], mmB[3]));
    nRegA = mxA * L2E;
    nRegB = mxB * L2E;
    #pragma unroll
    for (int rti = 0; rti < 2; ++rti)
      #pragma unroll
      for (int r = 0; r < 4; ++r) {
        PvA[rti][r] = __expf(a0A[rti][r] - mxA);   // max = 1
        PvB[rti][r] = __expf(a0B[rti][r] - mxB);
      }
  }

  auto publish = [&](int G, int wr, const f32x4 (&Pv)[2]) {
    float pl = 0.f;
    #pragma unroll
    for (int rti = 0; rti < 2; ++rti) {
      uint2 u;
      u.x = cvtpk_bf16(Pv[rti][0], Pv[rti][1]);
      u.y = cvtpk_bf16(Pv[rti][2], Pv[rti][3]);
      #pragma unroll
      for (int r = 0; r < 4; ++r) pl = fmaxf(pl, Pv[rti][r]);
      Pb[G][wr][c * 32 + ((8 * w + 4 * rti + hi) ^ sw2)] = u;
    }
    lamp[G][wr][c][slot] = pl;
  };

  publish(0, 0, PvA);
  publish(1, 0, PvB);
  BAR();

  const f32x4 z4 = {0.f, 0.f, 0.f, 0.f};

  // One chain's step. c2c/s2c/Dfc: current-step scale state (ready at entry).
  // eN = exp(em_{t+1}) raw-precomputed. Produces next-step scale state.
  auto STEP = [&](int t, int G, f32x4 (&Pv)[2], f32x4 (&c2c)[2],
                  float& s2c, int& Dfc, float& nRegX, const f32x4 (&eN)[2]) {
    const int rd = (t - 1) & 1, wr = t & 1;
    const uint2* prowR = &Pb[G][rd][c * 32];
    short8 bf[4];
    #pragma unroll
    for (int m = 0; m < 4; ++m) {
      union { uint4 u4; short8 h; } rb;
      rb.u4 = *(const uint4*)(&prowR[(8 * m + 2 * hi) ^ sw2]);
      bf[m] = rb.h;
    }
    const float* lr = &lamp[G][rd][c][0];
    f32x4 l0 = *(const f32x4*)(lr), l1 = *(const f32x4*)(lr + 4);
    f32x4 l2 = *(const f32x4*)(lr + 8), l3 = *(const f32x4*)(lr + 12);
    const int mt = maskLds[t * 32 + 16 * G + c];

    f32x4 acc[2];
    #pragma unroll
    for (int rti = 0; rti < 2; ++rti) {
      f32x4 aA = __builtin_amdgcn_mfma_f32_16x16x32_bf16(
          Ef[rti][1], bf[1],
          __builtin_amdgcn_mfma_f32_16x16x32_bf16(Ef[rti][0], bf[0], z4, 0, 0, 0),
          0, 0, 0);
      f32x4 aB = __builtin_amdgcn_mfma_f32_16x16x32_bf16(
          Ef[rti][3], bf[3],
          __builtin_amdgcn_mfma_f32_16x16x32_bf16(Ef[rti][2], bf[2], z4, 0, 0, 0),
          0, 0, 0);
      #pragma unroll
      for (int r = 0; r < 4; ++r) acc[rti][r] = aA[r] + aB[r];
    }

    // z_{t-1} from lamp (shadow work) -> next-step scale state
    f32x4 mm;
    #pragma unroll
    for (int r = 0; r < 4; ++r) mm[r] = fmaxf(fmaxf(l0[r], l1[r]), fmaxf(l2[r], l3[r]));
    int zC = expbits(fmaxf(fmaxf(mm[0], mm[1]), fmaxf(mm[2], mm[3])));
    int Dfn = 7 + (zC >> 2);
    Dfn = Dfn < -90 ? -90 : (Dfn > 110 ? 110 : Dfn);
    const float s2n = __uint_as_float((uint32_t)(127 - Dfn) << 23);

    unsigned long long bal = __ballot(mt > 0);
    if (bal == ~0ull) {
      #pragma unroll
      for (int rti = 0; rti < 2; ++rti)
        #pragma unroll
        for (int r = 0; r < 4; ++r) Pv[rti][r] = acc[rti][r] * c2c[rti][r];
    } else {
      #pragma unroll
      for (int rti = 0; rti < 2; ++rti)
        #pragma unroll
        for (int r = 0; r < 4; ++r) {
          float pn = acc[rti][r] * c2c[rti][r];
          float po = Pv[rti][r] * s2c;      // alpha held: P scales by 2^-Df
          Pv[rti][r] = (mt > 0) ? pn : po;
        }
    }
    nRegX += (float)Dfc;

    publish(G, wr, Pv);

    // carry next-step scale state
    #pragma unroll
    for (int rti = 0; rti < 2; ++rti)
      #pragma unroll
      for (int r = 0; r < 4; ++r) c2c[rti][r] = eN[rti][r] * s2n;
    s2c = s2n;
    Dfc = Dfn;
  };

  // controller init per chain: Df_1 = 7, c2_1 = exp(em_1)*2^-7
  int DfcA = 7, DfcB = 7;
  float s2cA = __uint_as_float((uint32_t)(127 - 7) << 23);
  float s2cB = s2cA;
  f32x4 c2cA[2], c2cB[2];
  #pragma unroll
  for (int rti = 0; rti < 2; ++rti)
    #pragma unroll
    for (int r = 0; r < 4; ++r) {
      c2cA[rti][r] = __expf(r1A[rti][r]) * s2cA;
      c2cB[rti][r] = __expf(r1B[rti][r]) * s2cB;
    }

  #pragma unroll 1
  for (int t = 1; t <= Tsz - 3; t += 2) {   // 1,3,...,117
    f32x4 eNA[2], eNB[2];
    #pragma unroll
    for (int rti = 0; rti < 2; ++rti)
      #pragma unroll
      for (int r = 0; r < 4; ++r) {
        eNA[rti][r] = __expf(rPA[rti][r]);  // exp(em_{t+1})
        eNB[rti][r] = __expf(rPB[rti][r]);
      }
    STEP(t, 0, PvA, c2cA, s2cA, DfcA, nRegA, eNA);
    STEP(t, 1, PvB, c2cB, s2cB, DfcB, nRegB, eNB);
    BAR();
    if (t + 3 < Tsz) {
      rPA[0] = *(const f32x4*)(epA + (size_t)(t + 3) * Ksz);
      rPA[1] = *(const f32x4*)(epA + (size_t)(t + 3) * Ksz + 16);
      rPB[0] = *(const f32x4*)(epB + (size_t)(t + 3) * Ksz);
      rPB[1] = *(const f32x4*)(epB + (size_t)(t + 3) * Ksz + 16);
    }
    f32x4 eMA[2], eMB[2];
    #pragma unroll
    for (int rti = 0; rti < 2; ++rti)
      #pragma unroll
      for (int r = 0; r < 4; ++r) {
        eMA[rti][r] = __expf(rQA[rti][r]);  // exp(em_{t+2})
        eMB[rti][r] = __expf(rQB[rti][r]);
      }
    STEP(t + 1, 0, PvA, c2cA, s2cA, DfcA, nRegA, eMA);
    STEP(t + 1, 1, PvB, c2cB, s2cB, DfcB, nRegB, eMB);
    BAR();
    if (t + 4 < Tsz) {
      rQA[0] = *(const f32x4*)(epA + (size_t)(t + 4) * Ksz);
      rQA[1] = *(const f32x4*)(epA + (size_t)(t + 4) * Ksz + 16);
      rQB[0] = *(const f32x4*)(epB + (size_t)(t + 4) * Ksz);
      rQB[1] = *(const f32x4*)(epB + (size_t)(t + 4) * Ksz + 16);
    }
  }
  {
    const f32x4 eZ[2] = {{0.f, 0.f, 0.f, 0.f}, {0.f, 0.f, 0.f, 0.f}};
    STEP(Tsz - 1, 0, PvA, c2cA, s2cA, DfcA, nRegA, eZ);   // t = 119
    STEP(Tsz - 1, 1, PvB, c2cB, s2cB, DfcB, nRegB, eZ);
    BAR();
  }

  // ---- lognorm per chain: nReg*ln2 + ln(sum_col P)
  {
    float ssA = ((PvA[0][0] + PvA[0][1]) + (PvA[0][2] + PvA[0][3]))
              + ((PvA[1][0] + PvA[1][1]) + (PvA[1][2] + PvA[1][3]));
    float ssB = ((PvB[0][0] + PvB[0][1]) + (PvB[0][2] + PvB[0][3]))
              + ((PvB[1][0] + PvB[1][1]) + (PvB[1][2] + PvB[1][3]));
    lamp[0][0][c][slot] = ssA;   // buffer 0 dead (last wr was 1)
    lamp[1][0][c][slot] = ssB;
  }
  BAR();
  float lognormA, lognormB;
  {
    const float* lrA = &lamp[0][0][c][0];
    const float* lrB = &lamp[1][0][c][0];
    float tA = 0.f, tB = 0.f;
    #pragma unroll
    for (int s = 0; s < 16; ++s) { tA += lrA[s]; tB += lrB[s]; }
    lognormA = nRegA * LN2 + __logf(tA);
    lognormB = nRegB * LN2 + __logf(tB);
  }

  // ---- score: slot covers t in [8s, 8s+8) for batches (A: b0+c, B: b0+16+c)
  float* scb = (float*)&Pb[0][0][0];   // reuse as [col 0..31][16]
  {
    const int t0 = 8 * slot;
    const int t1 = (t0 + 8 < Tsz) ? t0 + 8 : Tsz;
    #pragma unroll 1
    for (int G = 0; G < 2; ++G) {
      const int col = 16 * G + c;
      const int* tb = tag + (size_t)(b0 + col) * Tsz;
      const float* eb2 = emis + (size_t)(b0 + col) * Tsz * Ksz;
      float sc = 0.f;
      #pragma unroll 1
      for (int t = t0; t < t1; ++t) {
        int tg0 = tb[t];
        float m0 = (float)maskLds[t * 32 + col];
        sc += eb2[(size_t)t * Ksz + tg0] * m0;
        if (t + 1 < Tsz) {
          int tg1 = tb[t + 1];
          sc += Tg[(size_t)tg0 * Ksz + tg1] * m0 * (float)maskLds[(t + 1) * 32 + col];
        }
      }
      scb[col * 16 + slot] = sc;
    }
  }
  BAR();
  if (tid < 32) {                     // w=0; tid<16: c=tid (A); 16..31: c=tid-16 (B)
    const float* sr = &scb[tid * 16];
    float s2r = 0.f;
    #pragma unroll
    for (int s = 0; s < 16; ++s) s2r += sr[s];
    float ln = (tid < 16) ? lognormA : lognormB;
    nll[b0 + tid] = ln - s2r;
  }
}

// deterministic fixed-order mean over B values
__global__ __launch_bounds__(256) void crf_reduce(
    const float* __restrict__ nll, float* __restrict__ out) {
  __shared__ float buf[256];
  float s = 0.f;
  for (int i = threadIdx.x; i < Bsz; i += 256) s += nll[i];
  buf[threadIdx.x] = s;
  __syncthreads();
  #pragma unroll
  for (int off = 128; off > 0; off >>= 1) {
    if (threadIdx.x < off) buf[threadIdx.x] += buf[threadIdx.x + off];
    __syncthreads();
  }
  if (threadIdx.x == 0) out[0] = buf[0] / (float)Bsz;
}

extern "C" void kernel_launch(void* const* d_in, const int* in_sizes, int n_in,
                              void* d_out, int out_size, void* d_ws, size_t ws_size,
                              hipStream_t stream) {
  const float* emissions   = (const float*)d_in[0];
  const int*   tag_ids     = (const int*)d_in[1];
  const int*   mask        = (const int*)d_in[2];
  const float* transitions = (const float*)d_in[3];

  float* nll = (float*)d_ws;  // 2048 floats

  crf_fwd<<<Bsz / 32, 256, 0, stream>>>(emissions, tag_ids, mask, transitions, nll);
  crf_reduce<<<1, 256, 0, stream>>>(nll, (float*)d_out);
}